// Round 11
// baseline (870.874 us; speedup 1.0000x reference)
//
#include <hip/hip_runtime.h>
#include <math.h>

// MomentLayerRecurrent — round 19.
// r18: XCD swizzle null, FETCH rose with zero time change -> K-step stall is
// latency-structural (depth-1 dbuf drains the just-issued stage at every
// barrier; ~4700cy exposed per step). T3/T4 fix = depth-2 counted vmcnt
// (schedule proven correct in r15; r15 failed on GEOMETRY not mechanics).
// This round keeps r13's residency (2 blk/CU, 16 waves/CU) but shrinks the
// tile to 128x64 so 3 staging buffers fit: 3 x 24KB + 2.3KB = 76KB <= 80KB.
// Grid 1024 x 512thr (8 waves of 32x32). Steady state: stage kb+2, compute
// kb, vmcnt(3) -> kb+1 landed, kb+2 stays in flight across the barrier.
// FP DAG preserved exactly (same K order, same 16x32-col diag slots + tree,
// same 16-lane u_lin fold, same BN): absmax must stay 0.01757812.

#define BB 32
#define NN 512
#define SEQ 8
#define TG 7001
#define SVN (BB * NN)
#define BUFW 12288   // ushorts per staging buffer (24 KB)

typedef float f32x4 __attribute__((ext_vector_type(4)));
typedef short s16x8 __attribute__((ext_vector_type(8)));

__device__ __forceinline__ unsigned short bf16_rne(float v) {
    unsigned u = __float_as_uint(v);
    u += 0x7FFFu + ((u >> 16) & 1u);
    return (unsigned short)(u >> 16);
}
__device__ __forceinline__ float bf16_f(unsigned short h) {
    return __uint_as_float(((unsigned)h) << 16);
}
__device__ __forceinline__ void split2(float v, unsigned short& h, unsigned short& l) {
    unsigned short hh = bf16_rne(v);
    h = hh;
    l = bf16_rne(v - bf16_f(hh));
}

// TS index (ushort units): block = (r>>4)*16 + (k>>5); intra: ((k>>3)&3)*128 + (r&15)*8 + (k&7)
__device__ __forceinline__ size_t ts_idx(int r, int k) {
    return (size_t)(((r >> 4) * 16 + (k >> 5)) * 512 + ((k >> 3) & 3) * 128 + (r & 15) * 8 + (k & 7));
}

__device__ __forceinline__ float interp_tab(const float* __restrict__ tab, float x) {
    float t = (x + 10.0f) * 500.0f;
    t = fminf(fmaxf(t, 0.0f), 7000.0f);
    int i0 = (int)t;
    if (i0 > 6999) i0 = 6999;
    float fr = t - (float)i0;
    float a = tab[i0];
    float b = tab[i0 + 1];
    return fmaf(fr, b - a, a);
}

// global -> LDS direct copy, 16B per lane (dwordx4)
#define GLOAD_LDS16(GP, LP)                                                        \
    __builtin_amdgcn_global_load_lds(                                              \
        (const __attribute__((address_space(1))) unsigned int*)(const void*)(GP),  \
        (__attribute__((address_space(3))) unsigned int*)(void*)(LP), 16, 0, 0)

// ---------------- exp precompute (parallel) ----------------------------------
__global__ void k_exp(double* __restrict__ expP, double* __restrict__ expM) {
    int k = blockIdx.x * 256 + threadIdx.x;
    if (k >= TG) return;
    double x = -10.0 + (14.0 / 7000.0) * k;
    expP[k] = exp(x * x);
    expM[k] = exp(-x * x);
}

// ---------------- chained cumtrapz scans, y staged in LDS --------------------
__device__ double blk_exscan(double part, double* wsum) {
    int t = threadIdx.x, lane = t & 63, wid = t >> 6;
    double run = part;
    #pragma unroll
    for (int off = 1; off < 64; off <<= 1) {
        double nv = __shfl_up(run, off);
        if (lane >= off) run += nv;
    }
    if (lane == 63) wsum[wid] = run;
    __syncthreads();
    if (t < 16) {
        double v = wsum[t];
        #pragma unroll
        for (int off = 1; off < 16; off <<= 1) {
            double nv = __shfl_up(v, off);
            if (lane >= off) v += nv;
        }
        wsum[t] = v;
    }
    __syncthreads();
    double base = (wid > 0) ? wsum[wid - 1] : 0.0;
    double ex = base + run - part;
    __syncthreads();
    return ex;
}

__global__ __launch_bounds__(1024)
void k_scan(const double* __restrict__ expP, const double* __restrict__ expM,
            float* __restrict__ GT, float* __restrict__ GI, float* __restrict__ HI) {
    __shared__ double ys[7008];
    __shared__ double wsum[16];
    const int t = threadIdx.x;
    const double dx = 14.0 / 7000.0;
    int k0 = t * 7, k1 = k0 + 7;
    if (k1 > TG) k1 = TG;
    if (k0 > TG) k0 = TG;
    int kls = (k0 < 1) ? 1 : k0;

    for (int k = k0; k < k1; ++k) ys[k] = expM[k];
    __syncthreads();

    double tmp[7];
    {
        double part = 0.0;
        for (int k = kls; k < k1; ++k) part += 0.5 * (ys[k - 1] + ys[k]) * dx;
        double run = blk_exscan(part, wsum) + exp(-100.0) / 20.0;
        int c = 0;
        for (int k = k0; k < k1; ++k) {
            if (k >= 1) run += 0.5 * (ys[k - 1] + ys[k]) * dx;
            tmp[c] = expP[k] * run;
            GT[k] = (float)tmp[c];
            ++c;
        }
        __syncthreads();
        c = 0;
        for (int k = k0; k < k1; ++k) ys[k] = tmp[c++];
        __syncthreads();
    }
    {
        double part = 0.0;
        for (int k = kls; k < k1; ++k) part += 0.5 * (ys[k - 1] + ys[k]) * dx;
        double run = blk_exscan(part, wsum);
        for (int k = k0; k < k1; ++k) {
            if (k >= 1) run += 0.5 * (ys[k - 1] + ys[k]) * dx;
            GI[k] = (float)run;
        }
        __syncthreads();
    }
    {
        double part = 0.0;
        for (int k = kls; k < k1; ++k) {
            double ya = expM[k - 1] * ys[k - 1] * ys[k - 1];
            double yb = expM[k] * ys[k] * ys[k];
            part += 0.5 * (ya + yb) * dx;
        }
        double run = blk_exscan(part, wsum);
        int c = 0;
        for (int k = k0; k < k1; ++k) {
            if (k >= 1) {
                double ya = expM[k - 1] * ys[k - 1] * ys[k - 1];
                double yb = expM[k] * ys[k] * ys[k];
                run += 0.5 * (ya + yb) * dx;
            }
            tmp[c++] = run;
        }
        __syncthreads();
        c = 0;
        for (int k = k0; k < k1; ++k) ys[k] = tmp[c++];
        __syncthreads();
    }
    {
        double part = 0.0;
        for (int k = kls; k < k1; ++k)
            part += 0.5 * (expP[k - 1] * ys[k - 1] + expP[k] * ys[k]) * dx;
        double run = blk_exscan(part, wsum);
        for (int k = k0; k < k1; ++k) {
            if (k >= 1) run += 0.5 * (expP[k - 1] * ys[k - 1] + expP[k] * ys[k]) * dx;
            HI[k] = (float)run;
        }
    }
}

// ---------------- split-to-TS kernels ----------------------------------------
__global__ void k_splitW(const float* __restrict__ W,
                         unsigned short* __restrict__ Wh, unsigned short* __restrict__ Wl) {
    int t = blockIdx.x * 256 + threadIdx.x;
    int r = t >> 6, c8 = t & 63;
    int k = c8 * 8;
    const float* src = W + (size_t)r * NN + k;
    s16x8 hv, lv;
    #pragma unroll
    for (int q = 0; q < 8; ++q) {
        unsigned short h, l;
        split2(src[q], h, l);
        hv[q] = (short)h; lv[q] = (short)l;
    }
    size_t o = ts_idx(r, k);
    *reinterpret_cast<s16x8*>(Wh + o) = hv;
    *reinterpret_cast<s16x8*>(Wl + o) = lv;
}

__global__ void k_splitQ(const float* __restrict__ rho, const float* __restrict__ s,
                         unsigned short* __restrict__ Qh, unsigned short* __restrict__ Ql) {
    int t = blockIdx.x * 256 + threadIdx.x;
    int b = t >> 15;
    int rem = t & 32767;
    int r = rem >> 6, c8 = rem & 63;
    int k = c8 * 8;
    const float* src = rho + ((size_t)b * NN + r) * NN + k;
    const float* sb = s + b * NN;
    float si = sb[r];
    s16x8 hv, lv;
    #pragma unroll
    for (int q = 0; q < 8; ++q) {
        float v = src[q] * si * sb[k + q];
        unsigned short h, l;
        split2(v, h, l);
        hv[q] = (short)h; lv[q] = (short)l;
    }
    size_t o = (size_t)b * NN * NN + ts_idx(r, k);
    *reinterpret_cast<s16x8*>(Qh + o) = hv;
    *reinterpret_cast<s16x8*>(Ql + o) = lv;
}

// 3-pass split-bf16 MFMA over a 2x2 accumulator grid (32x32 wave tile)
#define MFMAF(AH, AL, BH, BL)                                                  \
    {                                                                          \
        _Pragma("unroll") for (int m_ = 0; m_ < 2; ++m_)                       \
            _Pragma("unroll") for (int n_ = 0; n_ < 2; ++n_)                   \
                acc[m_][n_] = __builtin_amdgcn_mfma_f32_16x16x32_bf16(         \
                    AH[m_], BH[n_], acc[m_][n_], 0, 0, 0);                     \
        _Pragma("unroll") for (int m_ = 0; m_ < 2; ++m_)                       \
            _Pragma("unroll") for (int n_ = 0; n_ < 2; ++n_)                   \
                acc[m_][n_] = __builtin_amdgcn_mfma_f32_16x16x32_bf16(         \
                    AL[m_], BH[n_], acc[m_][n_], 0, 0, 0);                     \
        _Pragma("unroll") for (int m_ = 0; m_ < 2; ++m_)                       \
            _Pragma("unroll") for (int n_ = 0; n_ < 2; ++n_)                   \
                acc[m_][n_] = __builtin_amdgcn_mfma_f32_16x16x32_bf16(         \
                    AH[m_], BL[n_], acc[m_][n_], 0, 0, 0);                     \
    }

// wave w stages its 3 chunks (1KB each) of the K-step
#define STAGE(BUF, KB)                                                         \
    {                                                                          \
        _Pragma("unroll") for (int q_ = 0; q_ < 3; ++q_)                       \
            GLOAD_LDS16(gp[q_] + (size_t)(KB) * 512,                           \
                        stg + (BUF) * BUFW + (c0 + q_) * 512);                 \
    }

// ---- LDS-staged TS MFMA GEMM, 128x64 tile, 8 waves, depth-2 pipeline --------
// Staging buffer (24 chunks of 1KB): [0:8)=Ah row-tiles, [8:16)=Al,
// [16:20)=Bh col-tiles, [20:24)=Bl. Wave w stages chunks w*3..w*3+3 and owns
// the 32x32 output at (wqm = w>>1, wqn = w&1).
template <int PHASE>
__global__ __launch_bounds__(512, 4)
void gemm_ts(const unsigned short* __restrict__ Ah, const unsigned short* __restrict__ Al,
             long aStride,
             const unsigned short* __restrict__ Bh, const unsigned short* __restrict__ Bl,
             long bStride,
             unsigned short* __restrict__ Oh, unsigned short* __restrict__ Ol,
             float* __restrict__ Of,
             const float* __restrict__ Wf, float* __restrict__ sv,
             const float* __restrict__ u_prev, const float* __restrict__ bvec,
             float* __restrict__ u_linT,
             const float* __restrict__ bn_w, const float* __restrict__ bmv,
             const float* __restrict__ u_e, const float* __restrict__ s_e2,
             const float* __restrict__ GT, const float* __restrict__ GI,
             const float* __restrict__ HI,
             float* __restrict__ u_next, float* __restrict__ s_next) {
    __shared__ __align__(16) unsigned short stg[3 * BUFW];   // 72 KB staging
    __shared__ float slS[192], chS[192], snS[192];

    const int id = blockIdx.x;
    const int b = id >> 5;              // batch 0..31
    const int tile = id & 31;           // 0..31
    const int yt = tile >> 3;           // 4 row-tiles of 128
    const int xt = tile & 7;            // 8 col-tiles of 64
    const int i0 = yt * 128, j0 = xt * 64;
    const int tid = threadIdx.x;
    const int w = tid >> 6, lane = tid & 63;
    const int wqm = w >> 1, wqn = w & 1;   // wave owns rows wqm*32.., cols wqn*32..
    const int laneo = lane * 8;

    // ---- per-wave staging source pointers (3 chunks) ----
    const int c0 = w * 3;
    const unsigned short* gp[3];
    #pragma unroll
    for (int q = 0; q < 3; ++q) {
        const int c = c0 + q;
        const unsigned short* src;
        if (c < 8)       src = Ah + (size_t)b * aStride + (size_t)((i0 >> 4) + c) * 8192;
        else if (c < 16) src = Al + (size_t)b * aStride + (size_t)((i0 >> 4) + c - 8) * 8192;
        else if (c < 20) src = Bh + (size_t)b * bStride + (size_t)((j0 >> 4) + c - 16) * 8192;
        else             src = Bl + (size_t)b * bStride + (size_t)((j0 >> 4) + c - 20) * 8192;
        gp[q] = src + laneo;
    }

    // first two K-tiles in flight under the prologue
    STAGE(0, 0);
    STAGE(1, 1);

    // ---- prologue ----
    if (PHASE == 0) {
        // u_lin fold: 16 rows x 16 segs of 32 floats (same per-row DAG as r13)
        if (tid < 256) {
            const int row = tile * 16 + (tid >> 4);
            const int seg = tid & 15;
            const float4* wr = (const float4*)(Wf + (size_t)row * NN + seg * 32);
            const float4* ur = (const float4*)(u_prev + b * NN + seg * 32);
            float a0 = 0.f, a1 = 0.f, a2 = 0.f, a3 = 0.f;
            #pragma unroll
            for (int kk = 0; kk < 8; ++kk) {
                float4 wv = wr[kk], uv = ur[kk];
                a0 = fmaf(wv.x, uv.x, a0);
                a1 = fmaf(wv.y, uv.y, a1);
                a2 = fmaf(wv.z, uv.z, a2);
                a3 = fmaf(wv.w, uv.w, a3);
            }
            float au = (a0 + a1) + (a2 + a3);
            au += __shfl_xor(au, 1);
            au += __shfl_xor(au, 2);
            au += __shfl_xor(au, 4);
            au += __shfl_xor(au, 8);
            if (seg == 0) u_linT[row * BB + b] = au + bvec[row];
        }
    } else if (tid < 192) {
        // BN stats + activation: 128 rows (tid<128) + 64 cols (tid in [128,192))
        const int ii = (tid < 128) ? (i0 + tid) : (j0 + tid - 128);
        float vb[32];
        {
            const float4* ul = (const float4*)(u_linT + (size_t)ii * BB);
            #pragma unroll
            for (int q = 0; q < 8; ++q) {
                float4 t4 = ul[q];
                vb[q * 4 + 0] = t4.x; vb[q * 4 + 1] = t4.y;
                vb[q * 4 + 2] = t4.z; vb[q * 4 + 3] = t4.w;
            }
        }
        float m = 0.0f;
        #pragma unroll
        for (int bb = 0; bb < BB; ++bb) m += vb[bb];
        m *= (1.0f / BB);
        float v = 0.0f;
        #pragma unroll
        for (int bb = 0; bb < BB; ++bb) {
            float d = vb[bb] - m;
            v = fmaf(d, d, v);
        }
        v *= (1.0f / BB);
        float f = bn_w[ii] / sqrtf(v + 1e-5f);
        const int idx = b * NN + ii;
        // deterministic fixed-tree sum of the 16 diag slots
        float s2;
        {
            const float* svp = sv + idx;
            float q0 = (svp[0 * SVN] + svp[1 * SVN]) + (svp[2 * SVN] + svp[3 * SVN]);
            float q1 = (svp[4 * SVN] + svp[5 * SVN]) + (svp[6 * SVN] + svp[7 * SVN]);
            float q2 = (svp[8 * SVN] + svp[9 * SVN]) + (svp[10 * SVN] + svp[11 * SVN]);
            float q3 = (svp[12 * SVN] + svp[13 * SVN]) + (svp[14 * SVN] + svp[15 * SVN]);
            s2 = (q0 + q1) + (q2 + q3);
        }
        float s_l = sqrtf(fmaxf(s2, 0.0f));
        float un = fmaf(vb[b] - m, f, bmv[ii]) + u_e[idx];
        float sn = sqrtf(fmaf((s_l * s_l) * f, f, s_e2[idx]));
        const float SQL = 0.22360679774997896f;
        float ss = fmaxf(sn, 1e-6f);
        float inv = 1.0f / (ss * SQL);
        float ubx = fminf(fmaxf((1.0f - un) * inv, -10.0f), 4.0f);
        float lbx = fminf(fmaxf((0.0f - un) * inv, -10.0f), 4.0f);
        float dG = interp_tab(GI, ubx) - interp_tab(GI, lbx);
        float ua = 1.0f / fmaf(40.0f, dG, 5.0f);
        float dH = fmaxf(interp_tab(HI, ubx) - interp_tab(HI, lbx), 0.0f);
        float sa = sqrtf(3200.0f * dH * ua * ua * ua);
        float dg2 = interp_tab(GT, ubx) - interp_tab(GT, lbx);
        float ch = ua * ua * 40.0f * dg2 / (SQL * fmaxf(sa, 1e-9f));
        slS[tid] = s_l;
        chS[tid] = ch;
        snS[tid] = sa;
        if (yt == 0 && tid >= 128) {   // each column written exactly once
            u_next[idx] = ua;
            s_next[idx] = sa;
        }
    }

    f32x4 acc[2][2];
    #pragma unroll
    for (int m2 = 0; m2 < 2; ++m2)
        #pragma unroll
        for (int n2 = 0; n2 < 2; ++n2) acc[m2][n2] = (f32x4){0.f, 0.f, 0.f, 0.f};

    // pipeline fill: oldest 3 loads (buf0) guaranteed landed; buf1 in flight
    asm volatile("s_waitcnt vmcnt(3)" ::: "memory");
    __builtin_amdgcn_sched_barrier(0);
    __builtin_amdgcn_s_barrier();
    __builtin_amdgcn_sched_barrier(0);

    // ---- depth-2 pipelined K loop: counted vmcnt, raw barriers ----
    #pragma unroll
    for (int kb = 0; kb < 16; ++kb) {
        const int cur = kb % 3;
        if (kb < 14) STAGE((kb + 2) % 3, kb + 2);
        const unsigned short* lbuf = stg + cur * BUFW;
        s16x8 fah[2], fal[2], fbh[2], fbl[2];
        #pragma unroll
        for (int t = 0; t < 2; ++t) {
            fah[t] = *reinterpret_cast<const s16x8*>(lbuf + (wqm * 2 + t) * 512 + laneo);
            fal[t] = *reinterpret_cast<const s16x8*>(lbuf + (8 + wqm * 2 + t) * 512 + laneo);
            fbh[t] = *reinterpret_cast<const s16x8*>(lbuf + (16 + wqn * 2 + t) * 512 + laneo);
            fbl[t] = *reinterpret_cast<const s16x8*>(lbuf + (20 + wqn * 2 + t) * 512 + laneo);
        }
        MFMAF(fah, fal, fbh, fbl);
        // wait only for the NEXT buffer's loads; newest stage stays in flight
        if (kb < 14) {
            asm volatile("s_waitcnt vmcnt(3)" ::: "memory");
        } else if (kb == 14) {
            asm volatile("s_waitcnt vmcnt(0)" ::: "memory");
        }
        __builtin_amdgcn_sched_barrier(0);
        __builtin_amdgcn_s_barrier();
        __builtin_amdgcn_sched_barrier(0);
    }

    // ---- epilogue — C/D layout: col = lane&15, row = (lane>>4)*4 + reg ----
    const size_t bofs = (size_t)b * NN * NN;
    const int rb0 = i0 + wqm * 32 + (lane >> 4) * 4;
    const int cb0 = j0 + wqn * 32 + (lane & 15);

    if (PHASE == 0) {
        // diag partials: same 16x(32-col) slot partition + intra-slot DAG as r13
        float dp[8];
        #pragma unroll
        for (int m2 = 0; m2 < 2; ++m2)
            #pragma unroll
            for (int r = 0; r < 4; ++r) {
                int row = rb0 + m2 * 16 + r;
                const float* wrow = Wf + ((size_t)row << 9) + cb0;
                float s = 0.0f;
                #pragma unroll
                for (int n2 = 0; n2 < 2; ++n2) s = fmaf(acc[m2][n2][r], wrow[n2 * 16], s);
                dp[m2 * 4 + r] = s;
            }
        #pragma unroll
        for (int k = 0; k < 8; ++k) {
            #pragma unroll
            for (int off = 1; off < 16; off <<= 1) dp[k] += __shfl_xor(dp[k], off);
        }
        if ((lane & 15) == 0) {
            float* svslot = sv + (size_t)(xt * 2 + wqn) * SVN + b * NN;
            #pragma unroll
            for (int k = 0; k < 8; ++k) {
                int row = rb0 + (k >> 2) * 16 + (k & 3);
                svslot[row] = dp[k];
            }
        }
    }

    if (PHASE == 2) {
        // fp32 rho, staged row-major [32][32] in wave-private LDS, 1KB stores
        float* fS = (float*)stg + w * 1024;
        #pragma unroll
        for (int m2 = 0; m2 < 2; ++m2)
            #pragma unroll
            for (int r = 0; r < 4; ++r) {
                const int lr = m2 * 16 + (lane >> 4) * 4 + r;
                const float si = slS[wqm * 32 + lr], ci = chS[wqm * 32 + lr];
                const int row = i0 + wqm * 32 + lr;
                #pragma unroll
                for (int n2 = 0; n2 < 2; ++n2) {
                    const int lc = wqn * 32 + n2 * 16 + (lane & 15);
                    const float sj = slS[128 + lc], cj = chS[128 + lc];
                    const int col = j0 + lc;
                    float denom = si * sj;
                    float rv = (denom > 1e-12f) ? (acc[m2][n2][r] / fmaxf(denom, 1e-12f)) : 0.0f;
                    rv *= ci * cj;
                    if (row == col) rv = 1.0f;
                    fS[lr * 32 + n2 * 16 + (lane & 15)] = rv;
                }
            }
        #pragma unroll
        for (int inst = 0; inst < 4; ++inst) {
            const int row = i0 + wqm * 32 + inst * 8 + (lane >> 3);
            const int col = j0 + wqn * 32 + (lane & 7) * 4;
            *reinterpret_cast<f32x4*>(Of + bofs + ((size_t)row << 9) + col) =
                *reinterpret_cast<const f32x4*>(fS + inst * 256 + (lane >> 3) * 32 + (lane & 7) * 4);
        }
    } else {
        // split-bf16 output staged in wave-private LDS in global TS byte order
        unsigned short* hiS = stg + w * 2048;
        unsigned short* loS = hiS + 1024;
        const int laneconst = (((lane & 15) >> 3) << 7) + ((lane >> 4) << 5) + (lane & 7);
        #pragma unroll
        for (int m2 = 0; m2 < 2; ++m2)
            #pragma unroll
            for (int n2 = 0; n2 < 2; ++n2) {
                const int base = laneconst + m2 * 512 + n2 * 256;
                #pragma unroll
                for (int r = 0; r < 4; ++r) {
                    float v;
                    if (PHASE == 0) {
                        v = acc[m2][n2][r];
                    } else {
                        const int lr = wqm * 32 + m2 * 16 + (lane >> 4) * 4 + r;
                        const int lc = wqn * 32 + n2 * 16 + (lane & 15);
                        const float si = slS[lr], ci = chS[lr], qi = snS[lr];
                        const float sj = slS[128 + lc], cj = chS[128 + lc], qj = snS[128 + lc];
                        float denom = si * sj;
                        float rv = (denom > 1e-12f) ? (acc[m2][n2][r] / fmaxf(denom, 1e-12f)) : 0.0f;
                        rv *= ci * cj;
                        if (i0 + lr == j0 + lc) rv = 1.0f;
                        v = rv * qi * qj;
                    }
                    unsigned short h, l;
                    split2(v, h, l);
                    hiS[base + r * 8] = h;
                    loS[base + r * 8] = l;
                }
            }
        // wave-private copy-out: 2 TS blocks x (hi+lo), 1KB coalesced each
        #pragma unroll
        for (int t2 = 0; t2 < 2; ++t2) {
            const int gb = ((i0 >> 4) + wqm * 2 + t2) * 16 + (j0 >> 5) + wqn;
            *reinterpret_cast<s16x8*>(Oh + bofs + (size_t)gb * 512 + laneo) =
                *reinterpret_cast<const s16x8*>(hiS + t2 * 512 + laneo);
            *reinterpret_cast<s16x8*>(Ol + bofs + (size_t)gb * 512 + laneo) =
                *reinterpret_cast<const s16x8*>(loS + t2 * 512 + laneo);
        }
    }
}

// ---------------- external pathway -------------------------------------------
__global__ void k_ext_dots(const float* __restrict__ Wx, const float* __restrict__ bx,
                           const float* __restrict__ ux, const float* __restrict__ sx,
                           float* __restrict__ u_e, float* __restrict__ s_e2) {
    int gw = (blockIdx.x << 2) + (threadIdx.x >> 6);
    int lane = threadIdx.x & 63;
    int b = gw >> 9, i = gw & 511;
    const float* wr = Wx + (size_t)i * NN;
    const float* ub = ux + b * NN;
    const float* sb = sx + b * NN;
    float au = 0.0f, as2 = 0.0f;
    for (int j = lane; j < NN; j += 64) {
        float w = wr[j];
        float s = sb[j];
        au = fmaf(w, ub[j], au);
        as2 = fmaf(w * w, s * s, as2);
    }
    #pragma unroll
    for (int off = 32; off; off >>= 1) {
        au += __shfl_down(au, off);
        as2 += __shfl_down(as2, off);
    }
    if (lane == 0) {
        u_e[b * NN + i] = au + bx[i];
        s_e2[b * NN + i] = as2;
    }
}

__global__ void k_ext_stats(float* __restrict__ u_e, float* __restrict__ s_e2,
                            const float* __restrict__ wmx, const float* __restrict__ bmx) {
    int i = blockIdx.x * blockDim.x + threadIdx.x;
    if (i >= NN) return;
    float m = 0.0f;
    for (int b = 0; b < BB; ++b) m += u_e[b * NN + i];
    m *= (1.0f / BB);
    float v = 0.0f;
    for (int b = 0; b < BB; ++b) {
        float d = u_e[b * NN + i] - m;
        v = fmaf(d, d, v);
    }
    v *= (1.0f / BB);
    float f = wmx[i] / sqrtf(v + 1e-5f);
    float bm = bmx[i];
    for (int b = 0; b < BB; ++b) {
        u_e[b * NN + i] = fmaf(u_e[b * NN + i] - m, f, bm);
        s_e2[b * NN + i] *= f * f;
    }
}

// ---------------- launcher ---------------------------------------------------
extern "C" void kernel_launch(void* const* d_in, const int* in_sizes, int n_in,
                              void* d_out, int out_size, void* d_ws, size_t ws_size,
                              hipStream_t stream) {
    (void)in_sizes; (void)n_in; (void)out_size; (void)ws_size;
    const float* u_in       = (const float*)d_in[0];
    const float* s_in       = (const float*)d_in[1];
    const float* rho_in     = (const float*)d_in[2];
    const float* u_ext      = (const float*)d_in[3];
    const float* s_ext      = (const float*)d_in[4];
    const float* W          = (const float*)d_in[5];
    const float* bvec       = (const float*)d_in[6];
    const float* W_ext      = (const float*)d_in[7];
    const float* b_ext      = (const float*)d_in[8];
    const float* w_mean     = (const float*)d_in[9];
    const float* b_mean     = (const float*)d_in[10];
    const float* w_mean_ext = (const float*)d_in[11];
    const float* b_mean_ext = (const float*)d_in[12];

    float* out_u   = (float*)d_out;
    float* out_s   = out_u + BB * NN;
    float* out_rho = out_s + BB * NN;
    unsigned short* Qh = (unsigned short*)out_rho;
    unsigned short* Ql = Qh + (size_t)BB * NN * NN;

    char* base = (char*)d_ws;
    size_t off = 0;
    auto alloc = [&](size_t bytes) -> char* {
        char* ptr = base + off;
        off += (bytes + 255) & ~(size_t)255;
        return ptr;
    };
    unsigned short* T1h = (unsigned short*)alloc((size_t)BB * NN * NN * 2);
    unsigned short* T1l = (unsigned short*)alloc((size_t)BB * NN * NN * 2);
    unsigned short* Wh  = (unsigned short*)alloc((size_t)NN * NN * 2);
    unsigned short* Wl  = (unsigned short*)alloc((size_t)NN * NN * 2);
    double* expP = (double*)alloc(TG * 8);
    double* expM = (double*)alloc(TG * 8);
    float* GTt   = (float*)alloc(TG * 4);
    float* GIt   = (float*)alloc(TG * 4);
    float* HIt   = (float*)alloc(TG * 4);
    float* u_e   = (float*)alloc(BB * NN * 4);
    float* s_e2  = (float*)alloc(BB * NN * 4);
    float* uA    = (float*)alloc(BB * NN * 4);
    float* uB2   = (float*)alloc(BB * NN * 4);
    float* sA    = (float*)alloc(BB * NN * 4);
    float* sB2   = (float*)alloc(BB * NN * 4);
    float* u_linT = (float*)alloc(BB * NN * 4);
    float* sv    = (float*)alloc((size_t)16 * BB * NN * 4);   // 16 diag slots

    // prologue
    k_exp<<<28, 256, 0, stream>>>(expP, expM);
    k_scan<<<1, 1024, 0, stream>>>(expP, expM, GTt, GIt, HIt);
    k_splitW<<<128, 256, 0, stream>>>(W, Wh, Wl);
    k_splitQ<<<4096, 256, 0, stream>>>(rho_in, s_in, Qh, Ql);
    k_ext_dots<<<BB * NN / 4, 256, 0, stream>>>(W_ext, b_ext, u_ext, s_ext, u_e, s_e2);
    k_ext_stats<<<2, 256, 0, stream>>>(u_e, s_e2, w_mean_ext, b_mean_ext);

    const float* cu = u_in;

    for (int t = 0; t < SEQ; ++t) {
        // T1 = W @ Q (TS), diag slot stores into sv, balanced u_lin fold
        gemm_ts<0><<<1024, 512, 0, stream>>>(
            Wh, Wl, 0L, Qh, Ql, (long)NN * NN, T1h, T1l, nullptr,
            W, sv, cu, bvec, u_linT,
            nullptr, nullptr, nullptr, nullptr, nullptr, nullptr, nullptr,
            nullptr, nullptr);
        float* nu = (t == SEQ - 1) ? out_u : ((t & 1) ? uA : uB2);
        float* ns = (t == SEQ - 1) ? out_s : ((t & 1) ? sA : sB2);
        // C = T1 @ W^T, BN+activation prologue, rho epilogue
        if (t < SEQ - 1) {
            gemm_ts<1><<<1024, 512, 0, stream>>>(
                T1h, T1l, (long)NN * NN, Wh, Wl, 0L, Qh, Ql, nullptr,
                nullptr, sv, nullptr, nullptr, u_linT,
                w_mean, b_mean, u_e, s_e2, GTt, GIt, HIt, nu, ns);
        } else {
            gemm_ts<2><<<1024, 512, 0, stream>>>(
                T1h, T1l, (long)NN * NN, Wh, Wl, 0L, nullptr, nullptr, out_rho,
                nullptr, sv, nullptr, nullptr, u_linT,
                w_mean, b_mean, u_e, s_e2, GTt, GIt, HIt, nu, ns);
        }
        cu = nu;
    }
}

// Round 12
// 676.701 us; speedup vs baseline: 1.2869x; 1.2869x over previous
//
#include <hip/hip_runtime.h>
#include <math.h>

// MomentLayerRecurrent — round 20 (final): byte-identical resubmission of the
// round-13 build (benched 696.9us, absmax 0.01757812) — the session's best.
// Eight structural probes (r14-r19: symmetry cut, deep pipelines at two
// geometries, LDS-port rebalance, operand-split staging, XCD swizzle) were
// all null or regressive: depth>1 pipelining and cache-friendly geometry are
// mutually exclusive under the 64-160KB LDS budget, so the per-K-step drain
// barrier's exposed stage round-trip (~40us/gemm) is this decomposition's
// structural floor.

#define BB 32
#define NN 512
#define SEQ 8
#define TG 7001
#define SVN (BB * NN)

typedef float f32x4 __attribute__((ext_vector_type(4)));
typedef short s16x8 __attribute__((ext_vector_type(8)));

__device__ __forceinline__ unsigned short bf16_rne(float v) {
    unsigned u = __float_as_uint(v);
    u += 0x7FFFu + ((u >> 16) & 1u);
    return (unsigned short)(u >> 16);
}
__device__ __forceinline__ float bf16_f(unsigned short h) {
    return __uint_as_float(((unsigned)h) << 16);
}
__device__ __forceinline__ void split2(float v, unsigned short& h, unsigned short& l) {
    unsigned short hh = bf16_rne(v);
    h = hh;
    l = bf16_rne(v - bf16_f(hh));
}

// TS index (ushort units): block = (r>>4)*16 + (k>>5); intra: ((k>>3)&3)*128 + (r&15)*8 + (k&7)
__device__ __forceinline__ size_t ts_idx(int r, int k) {
    return (size_t)(((r >> 4) * 16 + (k >> 5)) * 512 + ((k >> 3) & 3) * 128 + (r & 15) * 8 + (k & 7));
}

__device__ __forceinline__ float interp_tab(const float* __restrict__ tab, float x) {
    float t = (x + 10.0f) * 500.0f;
    t = fminf(fmaxf(t, 0.0f), 7000.0f);
    int i0 = (int)t;
    if (i0 > 6999) i0 = 6999;
    float fr = t - (float)i0;
    float a = tab[i0];
    float b = tab[i0 + 1];
    return fmaf(fr, b - a, a);
}

// global -> LDS direct copy, 16B per lane (dwordx4)
#define GLOAD_LDS16(GP, LP)                                                        \
    __builtin_amdgcn_global_load_lds(                                              \
        (const __attribute__((address_space(1))) unsigned int*)(const void*)(GP),  \
        (__attribute__((address_space(3))) unsigned int*)(void*)(LP), 16, 0, 0)

// ---------------- exp precompute (parallel) ----------------------------------
__global__ void k_exp(double* __restrict__ expP, double* __restrict__ expM) {
    int k = blockIdx.x * 256 + threadIdx.x;
    if (k >= TG) return;
    double x = -10.0 + (14.0 / 7000.0) * k;
    expP[k] = exp(x * x);
    expM[k] = exp(-x * x);
}

// ---------------- chained cumtrapz scans, y staged in LDS --------------------
__device__ double blk_exscan(double part, double* wsum) {
    int t = threadIdx.x, lane = t & 63, wid = t >> 6;
    double run = part;
    #pragma unroll
    for (int off = 1; off < 64; off <<= 1) {
        double nv = __shfl_up(run, off);
        if (lane >= off) run += nv;
    }
    if (lane == 63) wsum[wid] = run;
    __syncthreads();
    if (t < 16) {
        double v = wsum[t];
        #pragma unroll
        for (int off = 1; off < 16; off <<= 1) {
            double nv = __shfl_up(v, off);
            if (lane >= off) v += nv;
        }
        wsum[t] = v;
    }
    __syncthreads();
    double base = (wid > 0) ? wsum[wid - 1] : 0.0;
    double ex = base + run - part;
    __syncthreads();
    return ex;
}

__global__ __launch_bounds__(1024)
void k_scan(const double* __restrict__ expP, const double* __restrict__ expM,
            float* __restrict__ GT, float* __restrict__ GI, float* __restrict__ HI) {
    __shared__ double ys[7008];
    __shared__ double wsum[16];
    const int t = threadIdx.x;
    const double dx = 14.0 / 7000.0;
    int k0 = t * 7, k1 = k0 + 7;
    if (k1 > TG) k1 = TG;
    if (k0 > TG) k0 = TG;
    int kls = (k0 < 1) ? 1 : k0;

    for (int k = k0; k < k1; ++k) ys[k] = expM[k];
    __syncthreads();

    double tmp[7];
    {
        double part = 0.0;
        for (int k = kls; k < k1; ++k) part += 0.5 * (ys[k - 1] + ys[k]) * dx;
        double run = blk_exscan(part, wsum) + exp(-100.0) / 20.0;
        int c = 0;
        for (int k = k0; k < k1; ++k) {
            if (k >= 1) run += 0.5 * (ys[k - 1] + ys[k]) * dx;
            tmp[c] = expP[k] * run;
            GT[k] = (float)tmp[c];
            ++c;
        }
        __syncthreads();
        c = 0;
        for (int k = k0; k < k1; ++k) ys[k] = tmp[c++];
        __syncthreads();
    }
    {
        double part = 0.0;
        for (int k = kls; k < k1; ++k) part += 0.5 * (ys[k - 1] + ys[k]) * dx;
        double run = blk_exscan(part, wsum);
        for (int k = k0; k < k1; ++k) {
            if (k >= 1) run += 0.5 * (ys[k - 1] + ys[k]) * dx;
            GI[k] = (float)run;
        }
        __syncthreads();
    }
    {
        double part = 0.0;
        for (int k = kls; k < k1; ++k) {
            double ya = expM[k - 1] * ys[k - 1] * ys[k - 1];
            double yb = expM[k] * ys[k] * ys[k];
            part += 0.5 * (ya + yb) * dx;
        }
        double run = blk_exscan(part, wsum);
        int c = 0;
        for (int k = k0; k < k1; ++k) {
            if (k >= 1) {
                double ya = expM[k - 1] * ys[k - 1] * ys[k - 1];
                double yb = expM[k] * ys[k] * ys[k];
                run += 0.5 * (ya + yb) * dx;
            }
            tmp[c++] = run;
        }
        __syncthreads();
        c = 0;
        for (int k = k0; k < k1; ++k) ys[k] = tmp[c++];
        __syncthreads();
    }
    {
        double part = 0.0;
        for (int k = kls; k < k1; ++k)
            part += 0.5 * (expP[k - 1] * ys[k - 1] + expP[k] * ys[k]) * dx;
        double run = blk_exscan(part, wsum);
        for (int k = k0; k < k1; ++k) {
            if (k >= 1) run += 0.5 * (expP[k - 1] * ys[k - 1] + expP[k] * ys[k]) * dx;
            HI[k] = (float)run;
        }
    }
}

// ---------------- split-to-TS kernels ----------------------------------------
__global__ void k_splitW(const float* __restrict__ W,
                         unsigned short* __restrict__ Wh, unsigned short* __restrict__ Wl) {
    int t = blockIdx.x * 256 + threadIdx.x;
    int r = t >> 6, c8 = t & 63;
    int k = c8 * 8;
    const float* src = W + (size_t)r * NN + k;
    s16x8 hv, lv;
    #pragma unroll
    for (int q = 0; q < 8; ++q) {
        unsigned short h, l;
        split2(src[q], h, l);
        hv[q] = (short)h; lv[q] = (short)l;
    }
    size_t o = ts_idx(r, k);
    *reinterpret_cast<s16x8*>(Wh + o) = hv;
    *reinterpret_cast<s16x8*>(Wl + o) = lv;
}

__global__ void k_splitQ(const float* __restrict__ rho, const float* __restrict__ s,
                         unsigned short* __restrict__ Qh, unsigned short* __restrict__ Ql) {
    int t = blockIdx.x * 256 + threadIdx.x;
    int b = t >> 15;
    int rem = t & 32767;
    int r = rem >> 6, c8 = rem & 63;
    int k = c8 * 8;
    const float* src = rho + ((size_t)b * NN + r) * NN + k;
    const float* sb = s + b * NN;
    float si = sb[r];
    s16x8 hv, lv;
    #pragma unroll
    for (int q = 0; q < 8; ++q) {
        float v = src[q] * si * sb[k + q];
        unsigned short h, l;
        split2(v, h, l);
        hv[q] = (short)h; lv[q] = (short)l;
    }
    size_t o = (size_t)b * NN * NN + ts_idx(r, k);
    *reinterpret_cast<s16x8*>(Qh + o) = hv;
    *reinterpret_cast<s16x8*>(Ql + o) = lv;
}

#define MFMAF(AH, AL, BH, BL)                                                  \
    {                                                                          \
        _Pragma("unroll") for (int m_ = 0; m_ < 4; ++m_)                       \
            _Pragma("unroll") for (int n_ = 0; n_ < 2; ++n_)                   \
                acc[m_][n_] = __builtin_amdgcn_mfma_f32_16x16x32_bf16(         \
                    AH[m_], BH[n_], acc[m_][n_], 0, 0, 0);                     \
        _Pragma("unroll") for (int m_ = 0; m_ < 4; ++m_)                       \
            _Pragma("unroll") for (int n_ = 0; n_ < 2; ++n_)                   \
                acc[m_][n_] = __builtin_amdgcn_mfma_f32_16x16x32_bf16(         \
                    AL[m_], BH[n_], acc[m_][n_], 0, 0, 0);                     \
        _Pragma("unroll") for (int m_ = 0; m_ < 4; ++m_)                       \
            _Pragma("unroll") for (int n_ = 0; n_ < 2; ++n_)                   \
                acc[m_][n_] = __builtin_amdgcn_mfma_f32_16x16x32_bf16(         \
                    AH[m_], BL[n_], acc[m_][n_], 0, 0, 0);                     \
    }

// wave w stages 4 tiles of one array (arr = w>>1) into its chunk slots
#define STAGE(BUFOFF, KB)                                                      \
    {                                                                          \
        _Pragma("unroll") for (int q_ = 0; q_ < 4; ++q_)                       \
            GLOAD_LDS16(gsrc + (size_t)q_ * 8192 + (size_t)(KB) * 512,         \
                        ldst + (BUFOFF) + q_ * 512);                           \
    }

// ---------------- LDS-staged TS MFMA GEMM, 8 waves / 128x128 tile ------------
template <int PHASE>
__global__ __launch_bounds__(512, 4)
void gemm_ts(const unsigned short* __restrict__ Ah, const unsigned short* __restrict__ Al,
             long aStride,
             const unsigned short* __restrict__ Bh, const unsigned short* __restrict__ Bl,
             long bStride,
             unsigned short* __restrict__ Oh, unsigned short* __restrict__ Ol,
             float* __restrict__ Of,
             const float* __restrict__ Wf, float* __restrict__ sv,
             const float* __restrict__ u_prev, const float* __restrict__ bvec,
             float* __restrict__ u_linT,
             const float* __restrict__ bn_w, const float* __restrict__ bmv,
             const float* __restrict__ u_e, const float* __restrict__ s_e2,
             const float* __restrict__ GT, const float* __restrict__ GI,
             const float* __restrict__ HI,
             float* __restrict__ u_next, float* __restrict__ s_next) {
    // 64 KB: during K loop = 2x32KB staging double-buffer (32 chunks of 1KB:
    // [0:8)=Ah tiles, [8:16)=Al, [16:24)=Bh, [24:32)=Bl); in the epilogue the
    // same memory is per-wave output staging (8 x 8KB).
    __shared__ __align__(16) unsigned short stg[2 * 16384];
    __shared__ float slS[256], chS[256], snS[256];

    const int id = blockIdx.x;
    const int member = (id >> 3) & 3;
    const int g = (id & 7) | ((id >> 5) << 3);
    const int p = g & 3;
    const int b = g >> 2;
    const int xt = (PHASE == 0) ? p : member;
    const int yt = (PHASE == 0) ? member : p;
    const int i0 = yt * 128, j0 = xt * 128;
    const int tid = threadIdx.x;
    const int w = tid >> 6, lane = tid & 63;
    const int wqm = w >> 2, wqn = w & 3;   // wave owns rows wqm*64.., cols wqn*32..
    const int laneo = lane * 8;

    // ---- staging source/dest for this wave (arr = w>>1, 4 consecutive tiles)
    const unsigned short* gA_h = Ah + (size_t)b * aStride + (size_t)(i0 >> 4) * 8192 + laneo;
    const unsigned short* gA_l = Al + (size_t)b * aStride + (size_t)(i0 >> 4) * 8192 + laneo;
    const unsigned short* gB_h = Bh + (size_t)b * bStride + (size_t)(j0 >> 4) * 8192 + laneo;
    const unsigned short* gB_l = Bl + (size_t)b * bStride + (size_t)(j0 >> 4) * 8192 + laneo;
    const int arr = w >> 1;
    const unsigned short* gsrc =
        (arr == 0) ? gA_h : (arr == 1) ? gA_l : (arr == 2) ? gB_h : gB_l;
    gsrc += (size_t)((w & 1) * 4) * 8192;
    unsigned short* ldst = stg + (w * 4) * 512;

    // first K-tile staged while the prologue computes
    STAGE(0, 0);

    // ---- prologue ----
    if (PHASE == 0) {
        // u_lin fold: 32 rows x 16 segs of 32 floats (all 512 threads)
        const int tile16 = yt * 4 + xt;
        const int row = tile16 * 32 + (tid >> 4);
        const int seg = tid & 15;
        const float4* wr = (const float4*)(Wf + (size_t)row * NN + seg * 32);
        const float4* ur = (const float4*)(u_prev + b * NN + seg * 32);
        float a0 = 0.f, a1 = 0.f, a2 = 0.f, a3 = 0.f;
        #pragma unroll
        for (int kk = 0; kk < 8; ++kk) {
            float4 wv = wr[kk], uv = ur[kk];
            a0 = fmaf(wv.x, uv.x, a0);
            a1 = fmaf(wv.y, uv.y, a1);
            a2 = fmaf(wv.z, uv.z, a2);
            a3 = fmaf(wv.w, uv.w, a3);
        }
        float au = (a0 + a1) + (a2 + a3);
        au += __shfl_xor(au, 1);
        au += __shfl_xor(au, 2);
        au += __shfl_xor(au, 4);
        au += __shfl_xor(au, 8);
        if (seg == 0) u_linT[row * BB + b] = au + bvec[row];
    } else if (tid < 256) {
        // BN stats + activation; u_linT is [N x B] -> contiguous float4 reads
        const int ii = (tid < 128) ? (i0 + tid) : (j0 + tid - 128);
        float vb[32];
        {
            const float4* ul = (const float4*)(u_linT + (size_t)ii * BB);
            #pragma unroll
            for (int q = 0; q < 8; ++q) {
                float4 t4 = ul[q];
                vb[q * 4 + 0] = t4.x; vb[q * 4 + 1] = t4.y;
                vb[q * 4 + 2] = t4.z; vb[q * 4 + 3] = t4.w;
            }
        }
        float m = 0.0f;
        #pragma unroll
        for (int bb = 0; bb < BB; ++bb) m += vb[bb];
        m *= (1.0f / BB);
        float v = 0.0f;
        #pragma unroll
        for (int bb = 0; bb < BB; ++bb) {
            float d = vb[bb] - m;
            v = fmaf(d, d, v);
        }
        v *= (1.0f / BB);
        float f = bn_w[ii] / sqrtf(v + 1e-5f);
        const int idx = b * NN + ii;
        // deterministic fixed-tree sum of the 16 diag slots
        float s2;
        {
            const float* svp = sv + idx;
            float q0 = (svp[0 * SVN] + svp[1 * SVN]) + (svp[2 * SVN] + svp[3 * SVN]);
            float q1 = (svp[4 * SVN] + svp[5 * SVN]) + (svp[6 * SVN] + svp[7 * SVN]);
            float q2 = (svp[8 * SVN] + svp[9 * SVN]) + (svp[10 * SVN] + svp[11 * SVN]);
            float q3 = (svp[12 * SVN] + svp[13 * SVN]) + (svp[14 * SVN] + svp[15 * SVN]);
            s2 = (q0 + q1) + (q2 + q3);
        }
        float s_l = sqrtf(fmaxf(s2, 0.0f));
        float un = fmaf(vb[b] - m, f, bmv[ii]) + u_e[idx];
        float sn = sqrtf(fmaf((s_l * s_l) * f, f, s_e2[idx]));
        const float SQL = 0.22360679774997896f;
        float ss = fmaxf(sn, 1e-6f);
        float inv = 1.0f / (ss * SQL);
        float ubx = fminf(fmaxf((1.0f - un) * inv, -10.0f), 4.0f);
        float lbx = fminf(fmaxf((0.0f - un) * inv, -10.0f), 4.0f);
        float dG = interp_tab(GI, ubx) - interp_tab(GI, lbx);
        float ua = 1.0f / fmaf(40.0f, dG, 5.0f);
        float dH = fmaxf(interp_tab(HI, ubx) - interp_tab(HI, lbx), 0.0f);
        float sa = sqrtf(3200.0f * dH * ua * ua * ua);
        float dg2 = interp_tab(GT, ubx) - interp_tab(GT, lbx);
        float ch = ua * ua * 40.0f * dg2 / (SQL * fmaxf(sa, 1e-9f));
        slS[tid] = s_l;
        chS[tid] = ch;
        snS[tid] = sa;
        if (i0 == j0 && tid < 128) {
            u_next[idx] = ua;
            s_next[idx] = sa;
        }
    }

    f32x4 acc[4][2];
    #pragma unroll
    for (int m2 = 0; m2 < 4; ++m2)
        #pragma unroll
        for (int n2 = 0; n2 < 2; ++n2) acc[m2][n2] = (f32x4){0.f, 0.f, 0.f, 0.f};

    __syncthreads();   // buf0 staged (vmcnt drained); slS/chS/snS visible

    // ---- LDS-staged, double-buffered K loop (one barrier per K-step) ----
    #pragma unroll 2
    for (int kb = 0; kb < 16; ++kb) {
        const int cur = (kb & 1) * 16384;
        if (kb < 15) STAGE(16384 - cur, kb + 1);
        const unsigned short* lb = stg + cur;
        s16x8 fah[4], fal[4], fbh[2], fbl[2];
        #pragma unroll
        for (int t = 0; t < 4; ++t) {
            fah[t] = *reinterpret_cast<const s16x8*>(lb + (wqm * 4 + t) * 512 + laneo);
            fal[t] = *reinterpret_cast<const s16x8*>(lb + (8 + wqm * 4 + t) * 512 + laneo);
        }
        #pragma unroll
        for (int t = 0; t < 2; ++t) {
            fbh[t] = *reinterpret_cast<const s16x8*>(lb + (16 + wqn * 2 + t) * 512 + laneo);
            fbl[t] = *reinterpret_cast<const s16x8*>(lb + (24 + wqn * 2 + t) * 512 + laneo);
        }
        MFMAF(fah, fal, fbh, fbl);
        __syncthreads();   // readers done with cur; next buffer fully written
    }

    // ---- epilogue — C/D layout: col = lane&15, row = (lane>>4)*4 + reg ----
    const size_t bofs = (size_t)b * NN * NN;
    const int rb0 = i0 + wqm * 64 + (lane >> 4) * 4;
    const int cb0 = j0 + wqn * 32 + (lane & 15);

    if (PHASE == 0) {
        // diag partials: dp = sum_n acc[m][n][r] * W[row, col_n], xor-reduced;
        // plain stores into this block/wave's private slot (deterministic)
        float dp[16];
        #pragma unroll
        for (int m2 = 0; m2 < 4; ++m2)
            #pragma unroll
            for (int r = 0; r < 4; ++r) {
                int row = rb0 + m2 * 16 + r;
                const float* wrow = Wf + ((size_t)row << 9) + cb0;
                float s = 0.0f;
                #pragma unroll
                for (int n2 = 0; n2 < 2; ++n2) s = fmaf(acc[m2][n2][r], wrow[n2 * 16], s);
                dp[m2 * 4 + r] = s;
            }
        #pragma unroll
        for (int k = 0; k < 16; ++k) {
            #pragma unroll
            for (int off = 1; off < 16; off <<= 1) dp[k] += __shfl_xor(dp[k], off);
        }
        if ((lane & 15) == 0) {
            float* svslot = sv + (size_t)(xt * 4 + wqn) * SVN + b * NN;
            #pragma unroll
            for (int k = 0; k < 16; ++k) {
                int row = rb0 + (k >> 2) * 16 + (k & 3);
                svslot[row] = dp[k];
            }
        }
    }

    if (PHASE == 2) {
        // fp32 rho, staged row-major [64][32] in wave-private LDS, 1KB stores
        float* fS = (float*)stg + w * 2048;
        #pragma unroll
        for (int m2 = 0; m2 < 4; ++m2)
            #pragma unroll
            for (int r = 0; r < 4; ++r) {
                const int lr = m2 * 16 + (lane >> 4) * 4 + r;
                const float si = slS[wqm * 64 + lr], ci = chS[wqm * 64 + lr];
                const int row = i0 + wqm * 64 + lr;
                #pragma unroll
                for (int n2 = 0; n2 < 2; ++n2) {
                    const int lc = wqn * 32 + n2 * 16 + (lane & 15);
                    const float sj = slS[128 + lc], cj = chS[128 + lc];
                    const int col = j0 + lc;
                    float denom = si * sj;
                    float rv = (denom > 1e-12f) ? (acc[m2][n2][r] / fmaxf(denom, 1e-12f)) : 0.0f;
                    rv *= ci * cj;
                    if (row == col) rv = 1.0f;
                    fS[lr * 32 + n2 * 16 + (lane & 15)] = rv;
                }
            }
        #pragma unroll
        for (int inst = 0; inst < 8; ++inst) {
            const int row = i0 + wqm * 64 + inst * 8 + (lane >> 3);
            const int col = j0 + wqn * 32 + (lane & 7) * 4;
            *reinterpret_cast<f32x4*>(Of + bofs + ((size_t)row << 9) + col) =
                *reinterpret_cast<const f32x4*>(fS + inst * 256 + (lane >> 3) * 32 + (lane & 7) * 4);
        }
    } else {
        // split-bf16 output staged in wave-private LDS in global TS byte order
        unsigned short* hiS = stg + w * 4096;
        unsigned short* loS = hiS + 2048;
        const int laneconst = (((lane & 15) >> 3) << 7) + ((lane >> 4) << 5) + (lane & 7);
        #pragma unroll
        for (int m2 = 0; m2 < 4; ++m2)
            #pragma unroll
            for (int n2 = 0; n2 < 2; ++n2) {
                const int base = laneconst + m2 * 512 + n2 * 256;
                #pragma unroll
                for (int r = 0; r < 4; ++r) {
                    float v;
                    if (PHASE == 0) {
                        v = acc[m2][n2][r];
                    } else {
                        const int lr = wqm * 64 + m2 * 16 + (lane >> 4) * 4 + r;
                        const int lc = wqn * 32 + n2 * 16 + (lane & 15);
                        const float si = slS[lr], ci = chS[lr], qi = snS[lr];
                        const float sj = slS[128 + lc], cj = chS[128 + lc], qj = snS[128 + lc];
                        float denom = si * sj;
                        float rv = (denom > 1e-12f) ? (acc[m2][n2][r] / fmaxf(denom, 1e-12f)) : 0.0f;
                        rv *= ci * cj;
                        if (i0 + lr == j0 + lc) rv = 1.0f;
                        v = rv * qi * qj;
                    }
                    unsigned short h, l;
                    split2(v, h, l);
                    hiS[base + r * 8] = h;
                    loS[base + r * 8] = l;
                }
            }
        // wave-private copy-out: 4 TS blocks x (hi+lo), 1KB coalesced each
        #pragma unroll
        for (int lb = 0; lb < 4; ++lb) {
            const int gb = ((i0 >> 4) + wqm * 4 + lb) * 16 + (j0 >> 5) + wqn;
            *reinterpret_cast<s16x8*>(Oh + bofs + (size_t)gb * 512 + laneo) =
                *reinterpret_cast<const s16x8*>(hiS + lb * 512 + laneo);
            *reinterpret_cast<s16x8*>(Ol + bofs + (size_t)gb * 512 + laneo) =
                *reinterpret_cast<const s16x8*>(loS + lb * 512 + laneo);
        }
    }
}

// ---------------- external pathway -------------------------------------------
__global__ void k_ext_dots(const float* __restrict__ Wx, const float* __restrict__ bx,
                           const float* __restrict__ ux, const float* __restrict__ sx,
                           float* __restrict__ u_e, float* __restrict__ s_e2) {
    int gw = (blockIdx.x << 2) + (threadIdx.x >> 6);
    int lane = threadIdx.x & 63;
    int b = gw >> 9, i = gw & 511;
    const float* wr = Wx + (size_t)i * NN;
    const float* ub = ux + b * NN;
    const float* sb = sx + b * NN;
    float au = 0.0f, as2 = 0.0f;
    for (int j = lane; j < NN; j += 64) {
        float w = wr[j];
        float s = sb[j];
        au = fmaf(w, ub[j], au);
        as2 = fmaf(w * w, s * s, as2);
    }
    #pragma unroll
    for (int off = 32; off; off >>= 1) {
        au += __shfl_down(au, off);
        as2 += __shfl_down(as2, off);
    }
    if (lane == 0) {
        u_e[b * NN + i] = au + bx[i];
        s_e2[b * NN + i] = as2;
    }
}

__global__ void k_ext_stats(float* __restrict__ u_e, float* __restrict__ s_e2,
                            const float* __restrict__ wmx, const float* __restrict__ bmx) {
    int i = blockIdx.x * blockDim.x + threadIdx.x;
    if (i >= NN) return;
    float m = 0.0f;
    for (int b = 0; b < BB; ++b) m += u_e[b * NN + i];
    m *= (1.0f / BB);
    float v = 0.0f;
    for (int b = 0; b < BB; ++b) {
        float d = u_e[b * NN + i] - m;
        v = fmaf(d, d, v);
    }
    v *= (1.0f / BB);
    float f = wmx[i] / sqrtf(v + 1e-5f);
    float bm = bmx[i];
    for (int b = 0; b < BB; ++b) {
        u_e[b * NN + i] = fmaf(u_e[b * NN + i] - m, f, bm);
        s_e2[b * NN + i] *= f * f;
    }
}

// ---------------- launcher ---------------------------------------------------
extern "C" void kernel_launch(void* const* d_in, const int* in_sizes, int n_in,
                              void* d_out, int out_size, void* d_ws, size_t ws_size,
                              hipStream_t stream) {
    (void)in_sizes; (void)n_in; (void)out_size; (void)ws_size;
    const float* u_in       = (const float*)d_in[0];
    const float* s_in       = (const float*)d_in[1];
    const float* rho_in     = (const float*)d_in[2];
    const float* u_ext      = (const float*)d_in[3];
    const float* s_ext      = (const float*)d_in[4];
    const float* W          = (const float*)d_in[5];
    const float* bvec       = (const float*)d_in[6];
    const float* W_ext      = (const float*)d_in[7];
    const float* b_ext      = (const float*)d_in[8];
    const float* w_mean     = (const float*)d_in[9];
    const float* b_mean     = (const float*)d_in[10];
    const float* w_mean_ext = (const float*)d_in[11];
    const float* b_mean_ext = (const float*)d_in[12];

    float* out_u   = (float*)d_out;
    float* out_s   = out_u + BB * NN;
    float* out_rho = out_s + BB * NN;
    unsigned short* Qh = (unsigned short*)out_rho;
    unsigned short* Ql = Qh + (size_t)BB * NN * NN;

    char* base = (char*)d_ws;
    size_t off = 0;
    auto alloc = [&](size_t bytes) -> char* {
        char* ptr = base + off;
        off += (bytes + 255) & ~(size_t)255;
        return ptr;
    };
    unsigned short* T1h = (unsigned short*)alloc((size_t)BB * NN * NN * 2);
    unsigned short* T1l = (unsigned short*)alloc((size_t)BB * NN * NN * 2);
    unsigned short* Wh  = (unsigned short*)alloc((size_t)NN * NN * 2);
    unsigned short* Wl  = (unsigned short*)alloc((size_t)NN * NN * 2);
    double* expP = (double*)alloc(TG * 8);
    double* expM = (double*)alloc(TG * 8);
    float* GTt   = (float*)alloc(TG * 4);
    float* GIt   = (float*)alloc(TG * 4);
    float* HIt   = (float*)alloc(TG * 4);
    float* u_e   = (float*)alloc(BB * NN * 4);
    float* s_e2  = (float*)alloc(BB * NN * 4);
    float* uA    = (float*)alloc(BB * NN * 4);
    float* uB2   = (float*)alloc(BB * NN * 4);
    float* sA    = (float*)alloc(BB * NN * 4);
    float* sB2   = (float*)alloc(BB * NN * 4);
    float* u_linT = (float*)alloc(BB * NN * 4);
    float* sv    = (float*)alloc((size_t)16 * BB * NN * 4);   // 16 diag slots

    // prologue
    k_exp<<<28, 256, 0, stream>>>(expP, expM);
    k_scan<<<1, 1024, 0, stream>>>(expP, expM, GTt, GIt, HIt);
    k_splitW<<<128, 256, 0, stream>>>(W, Wh, Wl);
    k_splitQ<<<4096, 256, 0, stream>>>(rho_in, s_in, Qh, Ql);
    k_ext_dots<<<BB * NN / 4, 256, 0, stream>>>(W_ext, b_ext, u_ext, s_ext, u_e, s_e2);
    k_ext_stats<<<2, 256, 0, stream>>>(u_e, s_e2, w_mean_ext, b_mean_ext);

    const float* cu = u_in;

    for (int t = 0; t < SEQ; ++t) {
        // T1 = W @ Q (TS), diag slot stores into sv, balanced u_lin fold
        gemm_ts<0><<<512, 512, 0, stream>>>(
            Wh, Wl, 0L, Qh, Ql, (long)NN * NN, T1h, T1l, nullptr,
            W, sv, cu, bvec, u_linT,
            nullptr, nullptr, nullptr, nullptr, nullptr, nullptr, nullptr,
            nullptr, nullptr);
        float* nu = (t == SEQ - 1) ? out_u : ((t & 1) ? uA : uB2);
        float* ns = (t == SEQ - 1) ? out_s : ((t & 1) ? sA : sB2);
        // C = T1 @ W^T, BN+activation prologue, rho epilogue
        if (t < SEQ - 1) {
            gemm_ts<1><<<512, 512, 0, stream>>>(
                T1h, T1l, (long)NN * NN, Wh, Wl, 0L, Qh, Ql, nullptr,
                nullptr, sv, nullptr, nullptr, u_linT,
                w_mean, b_mean, u_e, s_e2, GTt, GIt, HIt, nu, ns);
        } else {
            gemm_ts<2><<<512, 512, 0, stream>>>(
                T1h, T1l, (long)NN * NN, Wh, Wl, 0L, nullptr, nullptr, out_rho,
                nullptr, sv, nullptr, nullptr, u_linT,
                w_mean, b_mean, u_e, s_e2, GTt, GIt, HIt, nu, ns);
        }
        cu = nu;
    }
}